// Round 1
// baseline (96.436 us; speedup 1.0000x reference)
//
#include <hip/hip_runtime.h>

#define M_PAD 512

// Pass 1: run-boundary detection over the sorted ray_indices.
// start[r] = first index with ray_indices[i]==r ; endx[r] = last+1.
// Rays never referenced keep start=endx=0 (memset) -> count 0.
__global__ void boundary_kernel(const int* __restrict__ ri,
                                int* __restrict__ start, int* __restrict__ endx,
                                int T) {
    int i = blockIdx.x * blockDim.x + threadIdx.x;
    if (i >= T) return;
    int r = ri[i];
    if (i == 0 || ri[i - 1] != r) start[r] = i;
    if (i == T - 1 || ri[i + 1] != r) endx[r] = i + 1;
}

// Pass 2: per-sample compute + coalesced scatter (sorted indices ->
// consecutive threads write consecutive pos of the same ray).
__global__ void main_kernel(const float* __restrict__ rays,
                            const int* __restrict__ ri,
                            const float* __restrict__ ts,
                            const float* __restrict__ te,
                            const int* __restrict__ start,
                            float* __restrict__ xyz_out,   // (T,4)
                            float* __restrict__ z_vals,    // (N,512)
                            float* __restrict__ dists,     // (N,512)
                            float* __restrict__ xyz_w,     // (N,512,4)
                            int T) {
    int i = blockIdx.x * blockDim.x + threadIdx.x;
    if (i >= T) return;
    int r = ri[i];
    float a = ts[i], b = te[i];
    float z = (a + b) * 0.5f;
    float d = b - a;
    const float* rc = rays + (size_t)r * 6;   // ~256 consecutive threads share r -> L1 broadcast
    float4 p = make_float4(fmaf(z, rc[3], rc[0]),
                           fmaf(z, rc[4], rc[1]),
                           fmaf(z, rc[5], rc[2]),
                           0.0f);
    reinterpret_cast<float4*>(xyz_out)[i] = p;
    int pos = i - start[r];
    if (pos < M_PAD) {                        // JAX scatter drops OOB; counts ~256<<512 anyway
        size_t idx = (size_t)r * M_PAD + pos;
        z_vals[idx] = z;
        dists[idx]  = d;
        reinterpret_cast<float4*>(xyz_w)[idx] = p;
    }
}

// Pass 3: ray_valid mask, zero the invalid tails, whole_valid=1.
// Writes are disjoint from main_kernel's (j>=cnt vs pos<cnt).
__global__ void fill_kernel(const int* __restrict__ start,
                            const int* __restrict__ endx,
                            float* __restrict__ ray_valid,   // (N,512)
                            float* __restrict__ z_vals,
                            float* __restrict__ dists,
                            float* __restrict__ xyz_w,
                            float* __restrict__ whole_valid, // (N,)
                            int total) {
    int idx = blockIdx.x * blockDim.x + threadIdx.x;
    if (idx >= total) return;
    int r = idx >> 9;            // /512
    int j = idx & (M_PAD - 1);
    int cnt = endx[r] - start[r];
    ray_valid[idx] = (j < cnt) ? 1.0f : 0.0f;
    if (j >= cnt) {
        z_vals[idx] = 0.0f;
        dists[idx]  = 0.0f;
        reinterpret_cast<float4*>(xyz_w)[idx] = make_float4(0.f, 0.f, 0.f, 0.f);
    }
    if (j == 0) whole_valid[r] = 1.0f;
}

extern "C" void kernel_launch(void* const* d_in, const int* in_sizes, int n_in,
                              void* d_out, int out_size, void* d_ws, size_t ws_size,
                              hipStream_t stream) {
    const float* rays = (const float*)d_in[0];  // (N,6)
    const int*   ri   = (const int*)d_in[1];    // (T,) sorted
    const float* ts   = (const float*)d_in[2];  // (T,)
    const float* te   = (const float*)d_in[3];  // (T,)
    const int N = in_sizes[0] / 6;
    const int T = in_sizes[1];

    // d_out layout: outputs concatenated flat in return order (all f32; bools as 0/1).
    float* out         = (float*)d_out;
    float* xyz_out     = out;                                    // T*4
    float* ray_valid   = xyz_out + (size_t)T * 4;                // N*512
    float* z_vals      = ray_valid + (size_t)N * M_PAD;          // N*512
    float* dists       = z_vals + (size_t)N * M_PAD;             // N*512
    float* whole_valid = dists + (size_t)N * M_PAD;              // N
    float* xyz_w       = whole_valid + N;                        // N*512*4

    int* start = (int*)d_ws;
    int* endx  = start + N;
    hipMemsetAsync(d_ws, 0, (size_t)2 * N * sizeof(int), stream);

    const int B = 256;
    boundary_kernel<<<(T + B - 1) / B, B, 0, stream>>>(ri, start, endx, T);
    main_kernel<<<(T + B - 1) / B, B, 0, stream>>>(rays, ri, ts, te, start,
                                                   xyz_out, z_vals, dists, xyz_w, T);
    const int total = N * M_PAD;
    fill_kernel<<<(total + B - 1) / B, B, 0, stream>>>(start, endx, ray_valid,
                                                       z_vals, dists, xyz_w,
                                                       whole_valid, total);
}